// Round 1
// baseline (319.822 us; speedup 1.0000x reference)
//
#include <hip/hip_runtime.h>
#include <stdint.h>

#define S_LEN 2048
#define DMODEL 1024
#define NHEAD 16
#define DK 64
#define BATCH 2

typedef __attribute__((ext_vector_type(8))) short bf16x8;
typedef __attribute__((ext_vector_type(4))) float f32x4;

__device__ __forceinline__ unsigned short f2bf(float f) {
  union { float f; unsigned u; } x; x.f = f;
  unsigned u = x.u;
  return (unsigned short)((u + 0x7fffu + ((u >> 16) & 1u)) >> 16);
}

__device__ __forceinline__ void gload_lds16(const void* g, void* l) {
  __builtin_amdgcn_global_load_lds(
      (const __attribute__((address_space(1))) unsigned int*)g,
      (__attribute__((address_space(3))) unsigned int*)l, 16, 0, 0);
}

// ---------------- cast fp32 -> bf16 (x and all weights) ----------------
__global__ __launch_bounds__(256) void cast_inputs(
    const float4* __restrict__ x,
    const float4* __restrict__ wq, const float4* __restrict__ wk,
    const float4* __restrict__ wv, const float4* __restrict__ wo,
    ushort4* __restrict__ xb, ushort4* __restrict__ wqkvb, ushort4* __restrict__ wob)
{
  int i = blockIdx.x * 256 + threadIdx.x;
  float4 v; ushort4* dst;
  if (i < (1 << 20)) {            // x: 4096*1024/4 float4
    v = x[i]; dst = xb + i;
  } else {
    int j = i - (1 << 20);
    int wsel = j >> 18;           // each W: 1024*1024/4 = 2^18 float4
    int o = j & ((1 << 18) - 1);
    const float4* src = (wsel == 0) ? wq : (wsel == 1) ? wk : (wsel == 2) ? wv : wo;
    v = src[o];
    dst = (wsel < 3) ? (wqkvb + ((size_t)wsel << 18) + o) : (wob + o);
  }
  ushort4 r;
  r.x = f2bf(v.x); r.y = f2bf(v.y); r.z = f2bf(v.z); r.w = f2bf(v.w);
  *dst = r;
}

// ---------------- RoPE cos/sin table: [B*S][32] float2 ----------------
__global__ __launch_bounds__(256) void rope_table(const int* __restrict__ pos,
                                                  float2* __restrict__ rope)
{
  int idx = blockIdx.x * 256 + threadIdx.x;   // 4096*32
  int ps = idx >> 5;
  int i = idx & 31;
  float p = (float)pos[ps];
  // inv_freq[i] = 10000^(-i/32) = 2^(-i*log2(10000)/32)
  float freq = exp2f(-(float)i * 0.41524101186092096f);
  float ang = p * freq;
  float s, c;
  __sincosf(ang, &s, &c);  // fast path; fall back below if precision issues
  // use precise versions to better match fp32 reference:
  s = sinf(ang); c = cosf(ang);
  rope[idx] = make_float2(c, s);
}

// ---------------- GEMM: C[m][n] = sum_k A[m][k]*Bw[n][k]  (bf16 in, fp32 acc)
// EPI=0: N=3072 (Q|K|V), epilogue applies RoPE to Q,K (scale 1/8 on Q) and
//        scatters bf16 to head-major [b][h][s][dk] buffers.
// EPI=1: N=1024, plain fp32 store to Out.
template<int EPI>
__global__ __launch_bounds__(256) void gemm_bt(
    const ushort* __restrict__ A, const ushort* __restrict__ Bw,
    const float2* __restrict__ rope,
    ushort* __restrict__ Qb, ushort* __restrict__ Kb, ushort* __restrict__ Vb,
    float* __restrict__ Out)
{
  constexpr int Kdim = 1024;
  __shared__ ushort At[128 * 64];
  __shared__ ushort Bt[128 * 64];
  const int bm = blockIdx.x & 31;       // 4096/128 = 32 tiles in M
  const int bn = blockIdx.x >> 5;
  const int tid = threadIdx.x;
  const int w = tid >> 6, lane = tid & 63;
  const int wr = w >> 1, wc = w & 1;
  const int lrow = lane >> 3;           // 0..7
  const int lch = lane & 7;             // 0..7

  f32x4 acc[4][4];
#pragma unroll
  for (int i = 0; i < 4; ++i)
#pragma unroll
    for (int j = 0; j < 4; ++j) acc[i][j] = (f32x4){0.f, 0.f, 0.f, 0.f};

  const size_t abase = (size_t)(bm * 128) * Kdim;
  const size_t bbase = (size_t)(bn * 128) * Kdim;

  for (int kt = 0; kt < Kdim / 64; ++kt) {
    // stage 128x64 A-tile and B-tile; XOR-swizzle the 16B chunk via the
    // GLOBAL source address (global_load_lds dest is linear: base+lane*16)
#pragma unroll
    for (int inst = 0; inst < 4; ++inst) {
      int r = w * 32 + inst * 8 + lrow;
      int gc = lch ^ (r & 7);
      gload_lds16(A + abase + (size_t)r * Kdim + kt * 64 + gc * 8,
                  &At[(w * 32 + inst * 8) * 64]);
      gload_lds16(Bw + bbase + (size_t)r * Kdim + kt * 64 + gc * 8,
                  &Bt[(w * 32 + inst * 8) * 64]);
    }
    __syncthreads();
#pragma unroll
    for (int kk = 0; kk < 2; ++kk) {
      bf16x8 af[4], bfv[4];
      int ch = kk * 4 + (lane >> 4);
#pragma unroll
      for (int fm = 0; fm < 4; ++fm) {
        int row = wr * 64 + fm * 16 + (lane & 15);
        af[fm] = *(const bf16x8*)&At[row * 64 + ((ch ^ (row & 7)) << 3)];
      }
#pragma unroll
      for (int fn = 0; fn < 4; ++fn) {
        int row = wc * 64 + fn * 16 + (lane & 15);
        bfv[fn] = *(const bf16x8*)&Bt[row * 64 + ((ch ^ (row & 7)) << 3)];
      }
#pragma unroll
      for (int fm = 0; fm < 4; ++fm)
#pragma unroll
        for (int fn = 0; fn < 4; ++fn)
          acc[fm][fn] = __builtin_amdgcn_mfma_f32_16x16x32_bf16(
              af[fm], bfv[fn], acc[fm][fn], 0, 0, 0);
    }
    __syncthreads();
  }

  if constexpr (EPI == 0) {
#pragma unroll
    for (int fn = 0; fn < 4; ++fn) {
      int gn = bn * 128 + wc * 64 + fn * 16 + (lane & 15);
      int sel = gn >> 10;               // 0=Q 1=K 2=V
      int col = gn & 1023;
      int h = col >> 6, d = col & 63;
      ushort* dst0 = (sel == 0) ? Qb : (sel == 1 ? Kb : Vb);
#pragma unroll
      for (int fm = 0; fm < 4; ++fm) {
        int gm0 = bm * 128 + wr * 64 + fm * 16 + ((lane >> 4) << 2);
#pragma unroll
        for (int j = 0; j < 4; ++j) {
          int gm = gm0 + j;
          float v = acc[fm][fn][j];
          float r;
          if (sel < 2) {
            float p = __shfl_xor(v, 1);
            float2 cs = rope[gm * 32 + (d >> 1)];
            r = (d & 1) ? (v * cs.x + p * cs.y) : (v * cs.x - p * cs.y);
            if (sel == 0) r *= 0.125f;  // fold 1/sqrt(dk)
          } else {
            r = v;
          }
          int b = gm >> 11, s = gm & 2047;
          dst0[((size_t)(b * NHEAD + h) * S_LEN + s) * DK + d] = f2bf(r);
        }
      }
    }
  } else {
#pragma unroll
    for (int fn = 0; fn < 4; ++fn) {
      int gn = bn * 128 + wc * 64 + fn * 16 + (lane & 15);
#pragma unroll
      for (int fm = 0; fm < 4; ++fm) {
        int gm0 = bm * 128 + wr * 64 + fm * 16 + ((lane >> 4) << 2);
#pragma unroll
        for (int j = 0; j < 4; ++j)
          Out[(size_t)(gm0 + j) * 1024 + gn] = acc[fm][fn][j];
      }
    }
  }
}

// ---------------- causal flash attention, bf16 MFMA ----------------
// grid: (B*H) * (S/64); block 256 = 4 waves, wave w owns q-rows [qt*64+w*16, +16)
__global__ __launch_bounds__(256) void attn_kernel(
    const ushort* __restrict__ Qb, const ushort* __restrict__ Kb,
    const ushort* __restrict__ Vb, ushort* __restrict__ Ob)
{
  __shared__ ushort Kt[64 * 64];        // [kv][d] swizzled
  __shared__ ushort Vt[64 * 64];        // [d][kv] swizzled (transposed)
  __shared__ ushort Pt[4][16 * 64];     // per-wave P buffer [q][kv] swizzled
  const int tid = threadIdx.x;
  const int w = tid >> 6, lane = tid & 63;
  const int bh = blockIdx.x >> 5;       // 0..31
  const int qt = blockIdx.x & 31;
  const size_t base = (size_t)bh * S_LEN * DK;
  const int qrow0 = qt * 64 + w * 16;

  bf16x8 qf[2];
  {
    const ushort* qp = Qb + base + (size_t)(qrow0 + (lane & 15)) * DK + ((lane >> 4) << 3);
    qf[0] = *(const bf16x8*)qp;
    qf[1] = *(const bf16x8*)(qp + 32);
  }
  f32x4 oacc[4];
  float m_r[4], l_r[4];
#pragma unroll
  for (int j = 0; j < 4; ++j) { oacc[j] = (f32x4){0.f,0.f,0.f,0.f}; m_r[j] = -INFINITY; l_r[j] = 0.f; }
  ushort* Pw = Pt[w];

  for (int kt = 0; kt <= qt; ++kt) {
    // ---- stage K (row-major, swizzled) and V (transposed, swizzled) ----
#pragma unroll
    for (int it = 0; it < 2; ++it) {
      int idx = it * 256 + tid;
      int row = idx >> 3, c = idx & 7;
      const size_t gsrc = base + (size_t)(kt * 64 + row) * DK + c * 8;
      bf16x8 kvv = *(const bf16x8*)(Kb + gsrc);
      *(bf16x8*)&Kt[row * 64 + ((c ^ (row & 7)) << 3)] = kvv;
      bf16x8 vv = *(const bf16x8*)(Vb + gsrc);
#pragma unroll
      for (int e = 0; e < 8; ++e) {
        int d = c * 8 + e;
        Vt[d * 64 + (((row >> 3) ^ (d & 7)) << 3) + (row & 7)] = ((const ushort*)&vv)[e];
      }
    }
    __syncthreads();

    // ---- S = Q K^T (scale already folded into Q) ----
    f32x4 sacc[4];
#pragma unroll
    for (int ct = 0; ct < 4; ++ct) sacc[ct] = (f32x4){0.f,0.f,0.f,0.f};
#pragma unroll
    for (int kk = 0; kk < 2; ++kk) {
      int ch = kk * 4 + (lane >> 4);
#pragma unroll
      for (int ct = 0; ct < 4; ++ct) {
        int row = ct * 16 + (lane & 15);
        bf16x8 kf = *(const bf16x8*)&Kt[row * 64 + ((ch ^ (row & 7)) << 3)];
        sacc[ct] = __builtin_amdgcn_mfma_f32_16x16x32_bf16(qf[kk], kf, sacc[ct], 0, 0, 0);
      }
    }
    if (kt == qt) {   // causal mask on diagonal tile
#pragma unroll
      for (int ct = 0; ct < 4; ++ct) {
        int kv = kt * 64 + ct * 16 + (lane & 15);
#pragma unroll
        for (int j = 0; j < 4; ++j) {
          int q = qrow0 + ((lane >> 4) << 2) + j;
          if (kv > q) sacc[ct][j] = -INFINITY;
        }
      }
    }

    // ---- online softmax (rows live on 16-lane groups) ----
    float pv[4][4];
#pragma unroll
    for (int j = 0; j < 4; ++j) {
      float mx = fmaxf(fmaxf(sacc[0][j], sacc[1][j]), fmaxf(sacc[2][j], sacc[3][j]));
      mx = fmaxf(mx, __shfl_xor(mx, 1));
      mx = fmaxf(mx, __shfl_xor(mx, 2));
      mx = fmaxf(mx, __shfl_xor(mx, 4));
      mx = fmaxf(mx, __shfl_xor(mx, 8));
      float mnew = fmaxf(m_r[j], mx);
      float sc = __expf(m_r[j] - mnew);
      m_r[j] = mnew;
      float rs = 0.f;
#pragma unroll
      for (int ct = 0; ct < 4; ++ct) {
        float p = __expf(sacc[ct][j] - mnew);
        pv[ct][j] = p; rs += p;
      }
      rs += __shfl_xor(rs, 1); rs += __shfl_xor(rs, 2);
      rs += __shfl_xor(rs, 4); rs += __shfl_xor(rs, 8);
      l_r[j] = l_r[j] * sc + rs;
#pragma unroll
      for (int dt = 0; dt < 4; ++dt) oacc[dt][j] *= sc;
    }

    // ---- P -> per-wave LDS (bf16), reload as MFMA A-fragments ----
#pragma unroll
    for (int ct = 0; ct < 4; ++ct)
#pragma unroll
      for (int j = 0; j < 4; ++j) {
        int row = ((lane >> 4) << 2) + j;
        int colc = ct * 2 + ((lane & 15) >> 3);
        Pw[row * 64 + ((colc ^ (row & 7)) << 3) + (lane & 7)] = f2bf(pv[ct][j]);
      }
#pragma unroll
    for (int kk = 0; kk < 2; ++kk) {
      int prow = lane & 15;
      int pch = kk * 4 + (lane >> 4);
      bf16x8 pf = *(const bf16x8*)&Pw[prow * 64 + ((pch ^ (prow & 7)) << 3)];
#pragma unroll
      for (int dt = 0; dt < 4; ++dt) {
        int vr = dt * 16 + (lane & 15);
        bf16x8 vf = *(const bf16x8*)&Vt[vr * 64 + ((pch ^ (vr & 7)) << 3)];
        oacc[dt] = __builtin_amdgcn_mfma_f32_16x16x32_bf16(pf, vf, oacc[dt], 0, 0, 0);
      }
    }
    __syncthreads();
  }

  // ---- epilogue: O/l -> bf16, [b][s][h*64+d] layout for the final GEMM ----
  const int b = bh >> 4, h = bh & 15;
#pragma unroll
  for (int dt = 0; dt < 4; ++dt)
#pragma unroll
    for (int j = 0; j < 4; ++j) {
      int q = qrow0 + ((lane >> 4) << 2) + j;
      float o = oacc[dt][j] / l_r[j];
      Ob[((size_t)b * S_LEN + q) * DMODEL + h * DK + dt * 16 + (lane & 15)] = f2bf(o);
    }
}

// ---------------- launcher ----------------
extern "C" void kernel_launch(void* const* d_in, const int* in_sizes, int n_in,
                              void* d_out, int out_size, void* d_ws, size_t ws_size,
                              hipStream_t stream) {
  const float* x  = (const float*)d_in[0];
  const int* pos  = (const int*)d_in[1];
  const float* wq = (const float*)d_in[2];
  const float* wk = (const float*)d_in[3];
  const float* wv = (const float*)d_in[4];
  const float* wo = (const float*)d_in[5];
  float* out = (float*)d_out;

  char* ws = (char*)d_ws;
  ushort* xb    = (ushort*)(ws);                    //  8 MB: x bf16 [4096][1024]
  ushort* wqkvb = (ushort*)(ws + (size_t)( 8u << 20)); //  6 MB: [3072][1024]
  ushort* wob   = (ushort*)(ws + (size_t)(14u << 20)); //  2 MB
  float2* rope  = (float2*)(ws + (size_t)(16u << 20)); //  1 MB: [4096][32]
  ushort* Qb    = (ushort*)(ws + (size_t)(17u << 20)); //  8 MB: [b][h][s][dk]
  ushort* Kb    = (ushort*)(ws + (size_t)(25u << 20));
  ushort* Vb    = (ushort*)(ws + (size_t)(33u << 20));
  ushort* Ob    = (ushort*)(ws + (size_t)(41u << 20)); //  8 MB: [b][s][d]

  cast_inputs<<<8192, 256, 0, stream>>>((const float4*)x, (const float4*)wq,
      (const float4*)wk, (const float4*)wv, (const float4*)wo,
      (ushort4*)xb, (ushort4*)wqkvb, (ushort4*)wob);
  rope_table<<<512, 256, 0, stream>>>(pos, rope);
  gemm_bt<0><<<32 * 24, 256, 0, stream>>>(xb, wqkvb, rope, Qb, Kb, Vb, nullptr);
  attn_kernel<<<32 * 32, 256, 0, stream>>>(Qb, Kb, Vb, Ob);
  gemm_bt<1><<<32 * 8, 256, 0, stream>>>(Ob, wob, rope, nullptr, nullptr, nullptr, out);
}

// Round 2
// 125.381 us; speedup vs baseline: 2.5508x; 2.5508x over previous
//
#include <hip/hip_runtime.h>
#include <stdint.h>

#define S_LEN 2048
#define DMODEL 1024
#define NHEAD 16
#define DK 64
#define BATCH 2

typedef __attribute__((ext_vector_type(8))) short bf16x8;
typedef __attribute__((ext_vector_type(4))) float f32x4;

__device__ __forceinline__ unsigned short f2bf(float f) {
  union { float f; unsigned u; } x; x.f = f;
  unsigned u = x.u;
  return (unsigned short)((u + 0x7fffu + ((u >> 16) & 1u)) >> 16);
}

__device__ __forceinline__ void gload_lds16(const void* g, void* l) {
  __builtin_amdgcn_global_load_lds(
      (const __attribute__((address_space(1))) unsigned int*)g,
      (__attribute__((address_space(3))) unsigned int*)l, 16, 0, 0);
}

// ---------------- cast fp32 -> bf16 (x and all weights) ----------------
__global__ __launch_bounds__(256) void cast_inputs(
    const float4* __restrict__ x,
    const float4* __restrict__ wq, const float4* __restrict__ wk,
    const float4* __restrict__ wv, const float4* __restrict__ wo,
    ushort4* __restrict__ xb, ushort4* __restrict__ wqkvb, ushort4* __restrict__ wob)
{
  int i = blockIdx.x * 256 + threadIdx.x;
  float4 v; ushort4* dst;
  if (i < (1 << 20)) {            // x: 4096*1024/4 float4
    v = x[i]; dst = xb + i;
  } else {
    int j = i - (1 << 20);
    int wsel = j >> 18;           // each W: 1024*1024/4 = 2^18 float4
    int o = j & ((1 << 18) - 1);
    const float4* src = (wsel == 0) ? wq : (wsel == 1) ? wk : (wsel == 2) ? wv : wo;
    v = src[o];
    dst = (wsel < 3) ? (wqkvb + ((size_t)wsel << 18) + o) : (wob + o);
  }
  ushort4 r;
  r.x = f2bf(v.x); r.y = f2bf(v.y); r.z = f2bf(v.z); r.w = f2bf(v.w);
  *dst = r;
}

// ---------------- RoPE cos/sin table: [B*S][32] float2 ----------------
__global__ __launch_bounds__(256) void rope_table(const int* __restrict__ pos,
                                                  float2* __restrict__ rope)
{
  int idx = blockIdx.x * 256 + threadIdx.x;   // 4096*32
  int ps = idx >> 5;
  int i = idx & 31;
  float p = (float)pos[ps];
  float freq = exp2f(-(float)i * 0.41524101186092096f);
  float ang = p * freq;
  rope[idx] = make_float2(cosf(ang), sinf(ang));
}

// ---------------- GEMM: C[m][n] = sum_k A[m][k]*Bw[n][k]  (bf16 in, fp32 acc)
// EPI=0: N=3072 (Q|K|V): RoPE on Q (scaled 1/8) and K -> [bh][s][64] bf16;
//        V -> TRANSPOSED global layout [bh][d][s] bf16 (feeds attention PV).
// EPI=1: N=1024, plain fp32 store to Out.
template<int EPI>
__global__ __launch_bounds__(256) void gemm_bt(
    const ushort* __restrict__ A, const ushort* __restrict__ Bw,
    const float2* __restrict__ rope,
    ushort* __restrict__ Qb, ushort* __restrict__ Kb, ushort* __restrict__ Vg,
    float* __restrict__ Out)
{
  constexpr int Kdim = 1024;
  __shared__ ushort At[128 * 64];
  __shared__ ushort Bt[128 * 64];
  const int bm = blockIdx.x & 31;       // 4096/128 = 32 tiles in M
  const int bn = blockIdx.x >> 5;
  const int tid = threadIdx.x;
  const int w = tid >> 6, lane = tid & 63;
  const int wr = w >> 1, wc = w & 1;
  const int lrow = lane >> 3;           // 0..7
  const int lch = lane & 7;             // 0..7

  f32x4 acc[4][4];
#pragma unroll
  for (int i = 0; i < 4; ++i)
#pragma unroll
    for (int j = 0; j < 4; ++j) acc[i][j] = (f32x4){0.f, 0.f, 0.f, 0.f};

  const size_t abase = (size_t)(bm * 128) * Kdim;
  const size_t bbase = (size_t)(bn * 128) * Kdim;

  for (int kt = 0; kt < Kdim / 64; ++kt) {
#pragma unroll
    for (int inst = 0; inst < 4; ++inst) {
      int r = w * 32 + inst * 8 + lrow;
      int gc = lch ^ (r & 7);
      gload_lds16(A + abase + (size_t)r * Kdim + kt * 64 + gc * 8,
                  &At[(w * 32 + inst * 8) * 64]);
      gload_lds16(Bw + bbase + (size_t)r * Kdim + kt * 64 + gc * 8,
                  &Bt[(w * 32 + inst * 8) * 64]);
    }
    __syncthreads();
    __builtin_amdgcn_s_setprio(1);
#pragma unroll
    for (int kk = 0; kk < 2; ++kk) {
      bf16x8 af[4], bfv[4];
      int ch = kk * 4 + (lane >> 4);
#pragma unroll
      for (int fm = 0; fm < 4; ++fm) {
        int row = wr * 64 + fm * 16 + (lane & 15);
        af[fm] = *(const bf16x8*)&At[row * 64 + ((ch ^ (row & 7)) << 3)];
      }
#pragma unroll
      for (int fn = 0; fn < 4; ++fn) {
        int row = wc * 64 + fn * 16 + (lane & 15);
        bfv[fn] = *(const bf16x8*)&Bt[row * 64 + ((ch ^ (row & 7)) << 3)];
      }
#pragma unroll
      for (int fm = 0; fm < 4; ++fm)
#pragma unroll
        for (int fn = 0; fn < 4; ++fn)
          acc[fm][fn] = __builtin_amdgcn_mfma_f32_16x16x32_bf16(
              af[fm], bfv[fn], acc[fm][fn], 0, 0, 0);
    }
    __builtin_amdgcn_s_setprio(0);
    __syncthreads();
  }

  if constexpr (EPI == 0) {
    const int sel = bn >> 3;            // block-uniform: 0=Q 1=K 2=V
    if (sel == 2) {
      // V: write transposed [bh][d][s], vectorized 8B (4 consecutive s)
#pragma unroll
      for (int fn = 0; fn < 4; ++fn) {
        int gn = bn * 128 + wc * 64 + fn * 16 + (lane & 15);
        int col = gn & 1023;
        int h = col >> 6, d = col & 63;
#pragma unroll
        for (int fm = 0; fm < 4; ++fm) {
          int gm0 = bm * 128 + wr * 64 + fm * 16 + ((lane >> 4) << 2);
          int b = gm0 >> 11, s0 = gm0 & 2047;
          uint lo = (uint)f2bf(acc[fm][fn][0]) | ((uint)f2bf(acc[fm][fn][1]) << 16);
          uint hi = (uint)f2bf(acc[fm][fn][2]) | ((uint)f2bf(acc[fm][fn][3]) << 16);
          uint2 val; val.x = lo; val.y = hi;
          *(uint2*)(Vg + ((size_t)((b * NHEAD + h) * DK + d) * S_LEN) + s0) = val;
        }
      }
    } else {
      ushort* dst0 = (sel == 0) ? Qb : Kb;
#pragma unroll
      for (int fn = 0; fn < 4; ++fn) {
        int gn = bn * 128 + wc * 64 + fn * 16 + (lane & 15);
        int col = gn & 1023;
        int h = col >> 6, d = col & 63;
#pragma unroll
        for (int fm = 0; fm < 4; ++fm) {
          int gm0 = bm * 128 + wr * 64 + fm * 16 + ((lane >> 4) << 2);
#pragma unroll
          for (int j = 0; j < 4; ++j) {
            int gm = gm0 + j;
            float v = acc[fm][fn][j];
            float p = __shfl_xor(v, 1);
            float2 cs = rope[gm * 32 + (d >> 1)];
            float r = (d & 1) ? (v * cs.x + p * cs.y) : (v * cs.x - p * cs.y);
            if (sel == 0) r *= 0.125f;  // fold 1/sqrt(dk)
            int b = gm >> 11, s = gm & 2047;
            dst0[((size_t)(b * NHEAD + h) * S_LEN + s) * DK + d] = f2bf(r);
          }
        }
      }
    }
  } else {
#pragma unroll
    for (int fn = 0; fn < 4; ++fn) {
      int gn = bn * 128 + wc * 64 + fn * 16 + (lane & 15);
#pragma unroll
      for (int fm = 0; fm < 4; ++fm) {
        int gm0 = bm * 128 + wr * 64 + fm * 16 + ((lane >> 4) << 2);
#pragma unroll
        for (int j = 0; j < 4; ++j)
          Out[(size_t)(gm0 + j) * 1024 + gn] = acc[fm][fn][j];
      }
    }
  }
}

// ---------------- causal flash attention, swapped-QK^T, bf16 MFMA ----------
// grid 512 = 32 bh * 16 pairs; block 256 = 4 waves. Block processes q-tiles
// {pair, 31-pair} (64 rows each; wave w owns 16 rows) -> 33 kv-tiles/block.
__global__ __launch_bounds__(256) void attn_kernel(
    const ushort* __restrict__ Qb, const ushort* __restrict__ Kb,
    const ushort* __restrict__ Vg, ushort* __restrict__ Ob)
{
  __shared__ ushort Kt[2][64 * 64];     // [kv][d] swizzled, double-buffered
  __shared__ ushort Vt[2][64 * 64];     // [d][kv] swizzled (from global V^T)
  __shared__ ushort Pt[4][16 * 64];     // per-wave P buffer [q][kv] swizzled
  const int tid = threadIdx.x;
  const int w = tid >> 6, lane = tid & 63;
  const int g = lane >> 4, q = lane & 15;
  const int bid = blockIdx.x;
  const int swz = (bid & 7) * 64 + (bid >> 3);   // XCD-chunked: same-bh together
  const int bh = swz >> 4, pair = swz & 15;
  const size_t kqbase = (size_t)bh * (S_LEN * DK);  // Q,K: [s][64]
  const size_t vbase  = (size_t)bh * (DK * S_LEN);  // V^T: [64][2048]
  const int b = bh >> 4, h = bh & 15;
  ushort* Pw = Pt[w];
  uint* Pw32 = (uint*)Pw;

  for (int t2 = 0; t2 < 2; ++t2) {
    const int qt = t2 ? (31 - pair) : pair;
    const int qrow0 = qt * 64 + w * 16;

    bf16x8 qf[2];
    {
      const ushort* qp = Qb + kqbase + (size_t)(qrow0 + q) * DK + g * 8;
      qf[0] = *(const bf16x8*)qp;
      qf[1] = *(const bf16x8*)(qp + 32);
    }
    f32x4 oacc[4];
#pragma unroll
    for (int dt = 0; dt < 4; ++dt) oacc[dt] = (f32x4){0.f, 0.f, 0.f, 0.f};
    float m_r = -INFINITY, l_r = 0.f;

    // ---- stage tile 0 into buffer 0 ----
#pragma unroll
    for (int pass = 0; pass < 2; ++pass) {
      int r0 = pass * 32 + w * 8;
      int r = r0 + (lane >> 3);
      int gc = (lane & 7) ^ (r & 7);
      gload_lds16(Kb + kqbase + (size_t)r * DK + gc * 8, &Kt[0][r0 * 64]);
      gload_lds16(Vg + vbase + (size_t)r * S_LEN + gc * 8, &Vt[0][r0 * 64]);
    }
    __syncthreads();

    int cur = 0;
    for (int kt = 0; kt <= qt; ++kt) {
      // ---- prefetch next tile into other buffer (overlaps compute) ----
      if (kt < qt) {
        int nxt = cur ^ 1, ktn = kt + 1;
#pragma unroll
        for (int pass = 0; pass < 2; ++pass) {
          int r0 = pass * 32 + w * 8;
          int r = r0 + (lane >> 3);
          int gc = (lane & 7) ^ (r & 7);
          gload_lds16(Kb + kqbase + (size_t)(ktn * 64 + r) * DK + gc * 8,
                      &Kt[nxt][r0 * 64]);
          gload_lds16(Vg + vbase + (size_t)r * S_LEN + ktn * 64 + gc * 8,
                      &Vt[nxt][r0 * 64]);
        }
      }

      // ---- S^T = K Q^T : lane owns column q (one q-row of S) ----
      f32x4 sacc[4];
#pragma unroll
      for (int ct = 0; ct < 4; ++ct) sacc[ct] = (f32x4){0.f, 0.f, 0.f, 0.f};
      __builtin_amdgcn_s_setprio(1);
#pragma unroll
      for (int kk = 0; kk < 2; ++kk) {
        int ch = kk * 4 + g;
#pragma unroll
        for (int ct = 0; ct < 4; ++ct) {
          int row = ct * 16 + q;
          bf16x8 kf = *(const bf16x8*)&Kt[cur][row * 64 + ((ch ^ (row & 7)) << 3)];
          sacc[ct] = __builtin_amdgcn_mfma_f32_16x16x32_bf16(kf, qf[kk], sacc[ct], 0, 0, 0);
        }
      }
      __builtin_amdgcn_s_setprio(0);

      if (kt == qt) {                   // causal mask on diagonal tile
        int qa = qrow0 + q;
#pragma unroll
        for (int ct = 0; ct < 4; ++ct) {
#pragma unroll
          for (int j = 0; j < 4; ++j) {
            int kv = qt * 64 + ct * 16 + g * 4 + j;
            if (kv > qa) sacc[ct][j] = -INFINITY;
          }
        }
      }

      // ---- online softmax: per-lane scalar state (lane owns one q-row) ----
      float mx = sacc[0][0];
#pragma unroll
      for (int ct = 0; ct < 4; ++ct)
#pragma unroll
        for (int j = 0; j < 4; ++j) mx = fmaxf(mx, sacc[ct][j]);
      mx = fmaxf(mx, __shfl_xor(mx, 16));
      mx = fmaxf(mx, __shfl_xor(mx, 32));
      if (mx > m_r + 8.0f) {            // defer-max: rescale only on growth
        float sc = __expf(m_r - mx);
        m_r = mx;
        l_r *= sc;
#pragma unroll
        for (int dt = 0; dt < 4; ++dt)
#pragma unroll
          for (int j = 0; j < 4; ++j) oacc[dt][j] *= sc;
      }
      float p[4][4];
      float rs = 0.f;
#pragma unroll
      for (int ct = 0; ct < 4; ++ct)
#pragma unroll
        for (int j = 0; j < 4; ++j) {
          float e = __expf(sacc[ct][j] - m_r);
          p[ct][j] = e; rs += e;
        }
      rs += __shfl_xor(rs, 16);
      rs += __shfl_xor(rs, 32);
      l_r += rs;

      // ---- P^T -> per-wave LDS (packed bf16 pairs along kv), reload as
      //      PV B-fragments (col=q, k-walk along kv) ----
#pragma unroll
      for (int ct = 0; ct < 4; ++ct)
#pragma unroll
        for (int i = 0; i < 2; ++i) {
          uint u = (uint)f2bf(p[ct][2 * i]) | ((uint)f2bf(p[ct][2 * i + 1]) << 16);
          int idx = 8 * ct + 2 * g + i;            // = kv/2
          Pw32[q * 32 + (((idx >> 2) ^ (q & 7)) << 2) + (idx & 3)] = u;
        }
      __builtin_amdgcn_s_setprio(1);
#pragma unroll
      for (int kk = 0; kk < 2; ++kk) {
        int ch = kk * 4 + g;
        bf16x8 pb = *(const bf16x8*)&Pw[q * 64 + ((ch ^ (q & 7)) << 3)];
#pragma unroll
        for (int dt = 0; dt < 4; ++dt) {
          int vr = dt * 16 + q;
          bf16x8 vf = *(const bf16x8*)&Vt[cur][vr * 64 + ((ch ^ (vr & 7)) << 3)];
          oacc[dt] = __builtin_amdgcn_mfma_f32_16x16x32_bf16(vf, pb, oacc[dt], 0, 0, 0);
        }
      }
      __builtin_amdgcn_s_setprio(0);
      __syncthreads();                  // drains prefetch vmcnt + buffer handoff
      cur ^= 1;
    }

    // ---- epilogue: O^T/l -> bf16, transpose via per-wave LDS, coalesced store
    float inv = 1.0f / l_r;
#pragma unroll
    for (int dt = 0; dt < 4; ++dt)
#pragma unroll
      for (int i = 0; i < 2; ++i) {
        uint u = (uint)f2bf(oacc[dt][2 * i] * inv) |
                 ((uint)f2bf(oacc[dt][2 * i + 1] * inv) << 16);
        int idx = dt * 8 + 2 * g + i;              // = d/2
        Pw32[q * 32 + (((idx >> 2) ^ (q & 7)) << 2) + (idx & 3)] = u;
      }
#pragma unroll
    for (int pass = 0; pass < 2; ++pass) {
      int qr = pass * 8 + (lane >> 3), c = lane & 7;
      bf16x8 vv = *(const bf16x8*)&Pw[qr * 64 + ((c ^ (qr & 7)) << 3)];
      *(bf16x8*)(Ob + ((size_t)(b * S_LEN) + qrow0 + qr) * DMODEL + h * DK + c * 8) = vv;
    }
  }
}

// ---------------- launcher ----------------
extern "C" void kernel_launch(void* const* d_in, const int* in_sizes, int n_in,
                              void* d_out, int out_size, void* d_ws, size_t ws_size,
                              hipStream_t stream) {
  const float* x  = (const float*)d_in[0];
  const int* pos  = (const int*)d_in[1];
  const float* wq = (const float*)d_in[2];
  const float* wk = (const float*)d_in[3];
  const float* wv = (const float*)d_in[4];
  const float* wo = (const float*)d_in[5];
  float* out = (float*)d_out;

  char* ws = (char*)d_ws;
  ushort* xb    = (ushort*)(ws);                       //  8 MB
  ushort* wqkvb = (ushort*)(ws + (size_t)( 8u << 20)); //  6 MB
  ushort* wob   = (ushort*)(ws + (size_t)(14u << 20)); //  2 MB
  float2* rope  = (float2*)(ws + (size_t)(16u << 20)); //  1 MB
  ushort* Qb    = (ushort*)(ws + (size_t)(17u << 20)); //  8 MB [bh][s][64]
  ushort* Kb    = (ushort*)(ws + (size_t)(25u << 20)); //  8 MB [bh][s][64]
  ushort* Vg    = (ushort*)(ws + (size_t)(33u << 20)); //  8 MB [bh][64][s]  (V^T)
  ushort* Ob    = (ushort*)(ws + (size_t)(41u << 20)); //  8 MB [b][s][d]

  cast_inputs<<<8192, 256, 0, stream>>>((const float4*)x, (const float4*)wq,
      (const float4*)wk, (const float4*)wv, (const float4*)wo,
      (ushort4*)xb, (ushort4*)wqkvb, (ushort4*)wob);
  rope_table<<<512, 256, 0, stream>>>(pos, rope);
  gemm_bt<0><<<32 * 24, 256, 0, stream>>>(xb, wqkvb, rope, Qb, Kb, Vg, nullptr);
  attn_kernel<<<512, 256, 0, stream>>>(Qb, Kb, Vg, Ob);
  gemm_bt<1><<<32 * 8, 256, 0, stream>>>(Ob, wob, rope, nullptr, nullptr, nullptr, out);
}